// Round 1
// baseline (984.467 us; speedup 1.0000x reference)
//
#include <hip/hip_runtime.h>
#include <math.h>

#define B 128
#define L 400
#define S 30
#define V 50000
#define EMB 128
#define H 512
#define M 512
#define OOV 30
#define H3 1536
#define VO (V + OOV)

// ---- output layout (floats) ----
#define O_HN    (B * VO)
#define O_WCTX  (O_HN + B * H)
#define O_WATTN (O_WCTX + B * M)
#define O_PGEN  (O_WATTN + B * L)
#define O_WCOV  (O_PGEN + B)

__global__ void k_zero(float* wscore, float* sscore) {
    int i = blockIdx.x * 256 + threadIdx.x;
    if (i < B * L) wscore[i] = 0.f;
    if (i < B * S) sscore[i] = 0.f;
}

// gi = y_emb @ Wih^T + bih ; gh = h @ Whh^T + bhh   (one block per b)
__global__ __launch_bounds__(256) void k_gru_mm(
        const float* __restrict__ emb, const int* __restrict__ y,
        const float* __restrict__ h,
        const float* __restrict__ Wih, const float* __restrict__ Whh,
        const float* __restrict__ bih, const float* __restrict__ bhh,
        float* __restrict__ yemb, float* __restrict__ gi, float* __restrict__ gh) {
    __shared__ float se[EMB];
    __shared__ float sh[H];
    int b = blockIdx.x, t = threadIdx.x;
    int yb = y[b];
    if (t < EMB) { float v = emb[(size_t)yb * EMB + t]; se[t] = v; yemb[b * EMB + t] = v; }
    sh[t] = h[b * H + t];
    sh[t + 256] = h[b * H + t + 256];
    __syncthreads();
    for (int j = t; j < H3; j += 256) {
        const float4* wi = (const float4*)(Wih + (size_t)j * EMB);
        float ai = bih[j];
#pragma unroll 8
        for (int k = 0; k < EMB / 4; ++k) {
            float4 w = wi[k];
            ai += w.x * se[4 * k] + w.y * se[4 * k + 1] + w.z * se[4 * k + 2] + w.w * se[4 * k + 3];
        }
        gi[b * H3 + j] = ai;
        const float4* wh = (const float4*)(Whh + (size_t)j * H);
        float ah = bhh[j];
#pragma unroll 8
        for (int k = 0; k < H / 4; ++k) {
            float4 w = wh[k];
            ah += w.x * sh[4 * k] + w.y * sh[4 * k + 1] + w.z * sh[4 * k + 2] + w.w * sh[4 * k + 3];
        }
        gh[b * H3 + j] = ah;
    }
}

__global__ void k_gru_gates(const float* __restrict__ gi, const float* __restrict__ gh,
                            const float* __restrict__ h, float* __restrict__ hnext) {
    int i = blockIdx.x * 256 + threadIdx.x;  // b*H + k
    int b = i >> 9, k = i & 511;
    float ir = gi[b * H3 + k], iz = gi[b * H3 + H + k], inn = gi[b * H3 + 2 * H + k];
    float hr = gh[b * H3 + k], hz = gh[b * H3 + H + k], hn = gh[b * H3 + 2 * H + k];
    float r = 1.f / (1.f + expf(-(ir + hr)));
    float z = 1.f / (1.f + expf(-(iz + hz)));
    float n = tanhf(inn + r * hn);
    hnext[i] = (1.f - z) * n + z * h[i];
}

__global__ __launch_bounds__(256) void k_dec_proj(
        const float* __restrict__ hlast,
        const float* __restrict__ Ww, const float* __restrict__ bw,
        const float* __restrict__ Ws, const float* __restrict__ bs,
        float* __restrict__ dpw, float* __restrict__ dps) {
    __shared__ float sh[H];
    int b = blockIdx.x, t = threadIdx.x;
    sh[t] = hlast[b * H + t]; sh[t + 256] = hlast[b * H + t + 256];
    __syncthreads();
    for (int d = t; d < H; d += 256) {
        const float4* w1 = (const float4*)(Ww + (size_t)d * H);
        const float4* w2 = (const float4*)(Ws + (size_t)d * H);
        float a1 = bw[d], a2 = bs[d];
#pragma unroll 8
        for (int k = 0; k < H / 4; ++k) {
            float4 u = w1[k]; float4 v = w2[k];
            float s0 = sh[4 * k], s1 = sh[4 * k + 1], s2 = sh[4 * k + 2], s3 = sh[4 * k + 3];
            a1 += u.x * s0 + u.y * s1 + u.z * s2 + u.w * s3;
            a2 += v.x * s0 + v.y * s1 + v.z * s2 + v.w * s3;
        }
        dpw[b * H + d] = a1; dps[b * H + d] = a2;
    }
}

// score[row] += sum_d v[d]*tanh( mem[row,:]@Wmp[d,:] + dproj[b,d] (+cov*covp[d]) )
// 64-row x 128-d tile per block, K=512; grid = (4 d-chunks, rows/64)
template <bool HAS_COV>
__global__ __launch_bounds__(256) void k_feat(
        const float* __restrict__ memb,   // [rows][M]
        const float* __restrict__ Wmp,    // [H][M]
        const float* __restrict__ dproj,  // [B][H]
        const float* __restrict__ cov,    // [B*Lr] or null
        const float* __restrict__ covp,   // [H]
        const float* __restrict__ vvec,   // [H]
        float* __restrict__ score,        // [B*Lr]
        int Lr) {
    __shared__ float As[64][68];    // [l][m]
    __shared__ float Bs[128][68];   // [d][m]
    int t = threadIdx.x;
    int tx = t & 15, ty = t >> 4;
    int rowBase = blockIdx.y * 64;
    int dBase = blockIdx.x * 128;

    float acc[4][8];
#pragma unroll
    for (int i = 0; i < 4; ++i)
#pragma unroll
        for (int j = 0; j < 8; ++j) acc[i][j] = 0.f;

    for (int kc = 0; kc < M; kc += 64) {
        int lc = tx * 4;
#pragma unroll
        for (int i = 0; i < 4; ++i) {
            int r = ty + i * 16;
            *(float4*)&As[r][lc] = *(const float4*)(memb + (size_t)(rowBase + r) * M + kc + lc);
        }
#pragma unroll
        for (int i = 0; i < 8; ++i) {
            int r = ty + i * 16;
            *(float4*)&Bs[r][lc] = *(const float4*)(Wmp + (size_t)(dBase + r) * M + kc + lc);
        }
        __syncthreads();
#pragma unroll 2
        for (int mm = 0; mm < 64; mm += 4) {
            float4 fa[4], fb[8];
#pragma unroll
            for (int i = 0; i < 4; ++i) fa[i] = *(const float4*)&As[ty + 16 * i][mm];
#pragma unroll
            for (int j = 0; j < 8; ++j) fb[j] = *(const float4*)&Bs[tx + 16 * j][mm];
#pragma unroll
            for (int i = 0; i < 4; ++i)
#pragma unroll
                for (int j = 0; j < 8; ++j)
                    acc[i][j] += fa[i].x * fb[j].x + fa[i].y * fb[j].y +
                                 fa[i].z * fb[j].z + fa[i].w * fb[j].w;
        }
        __syncthreads();
    }
#pragma unroll
    for (int i = 0; i < 4; ++i) {
        int row = rowBase + ty + 16 * i;
        int b = row / Lr;
        float cv = HAS_COV ? cov[row] : 0.f;
        float s = 0.f;
#pragma unroll
        for (int j = 0; j < 8; ++j) {
            int d = dBase + tx + 16 * j;
            float f = acc[i][j] + dproj[b * H + d];
            if (HAS_COV) f += cv * covp[d];
            s += vvec[d] * tanhf(f);
        }
#pragma unroll
        for (int off = 8; off; off >>= 1) s += __shfl_xor(s, off, 16);
        if (tx == 0) atomicAdd(&score[row], s);
    }
}

__global__ __launch_bounds__(256) void k_smax_word(
        const float* __restrict__ score, const float* __restrict__ mask,
        const float* __restrict__ cov, float* __restrict__ attn_out,
        float* __restrict__ cov_out) {
    __shared__ float sc[L];
    __shared__ float red[4];
    int b = blockIdx.x, t = threadIdx.x;
    float mx = -1e30f;
    for (int l = t; l < L; l += 256) { float s = score[b * L + l]; sc[l] = s; mx = fmaxf(mx, s); }
    for (int off = 32; off; off >>= 1) mx = fmaxf(mx, __shfl_xor(mx, off));
    if ((t & 63) == 0) red[t >> 6] = mx;
    __syncthreads();
    mx = fmaxf(fmaxf(red[0], red[1]), fmaxf(red[2], red[3]));
    __syncthreads();
    float sm = 0.f;
    for (int l = t; l < L; l += 256) { float e = expf(sc[l] - mx); sc[l] = e; sm += e; }
    for (int off = 32; off; off >>= 1) sm += __shfl_xor(sm, off);
    if ((t & 63) == 0) red[t >> 6] = sm;
    __syncthreads();
    float Z = red[0] + red[1] + red[2] + red[3];
    __syncthreads();
    float sm2 = 0.f;
    for (int l = t; l < L; l += 256) {
        float a = (sc[l] / Z) * mask[b * L + l];
        sc[l] = a; sm2 += a;
    }
    for (int off = 32; off; off >>= 1) sm2 += __shfl_xor(sm2, off);
    if ((t & 63) == 0) red[t >> 6] = sm2;
    __syncthreads();
    float Zm = red[0] + red[1] + red[2] + red[3] + 1e-10f;
    for (int l = t; l < L; l += 256) {
        float a = sc[l] / Zm;
        attn_out[b * L + l] = a;
        cov_out[b * L + l] = cov[b * L + l] + a;
    }
}

__global__ __launch_bounds__(128) void k_ctx_word(
        const float* __restrict__ attn, const float* __restrict__ memb,
        float* __restrict__ ctx) {
    __shared__ float sa[L];
    int b = blockIdx.x, t = threadIdx.x;  // 128 threads, float4 each
    for (int l = t; l < L; l += 128) sa[l] = attn[b * L + l];
    __syncthreads();
    float4 acc = make_float4(0.f, 0.f, 0.f, 0.f);
    for (int l = 0; l < L; ++l) {
        float4 m = ((const float4*)(memb + ((size_t)b * L + l) * M))[t];
        float a = sa[l];
        acc.x += a * m.x; acc.y += a * m.y; acc.z += a * m.z; acc.w += a * m.w;
    }
    ((float4*)(ctx + b * M))[t] = acc;
}

__global__ __launch_bounds__(256) void k_sent(
        const float* __restrict__ score, const float* __restrict__ mask,
        const float* __restrict__ memb, float* __restrict__ ctx) {
    __shared__ float sa[S], sa2[S], sm[S];
    int b = blockIdx.x, t = threadIdx.x;
    if (t < S) { sa[t] = score[b * S + t]; sm[t] = mask[b * S + t]; }
    __syncthreads();
    if (t < S) {
        float mx = -1e30f;
        for (int l = 0; l < S; ++l) mx = fmaxf(mx, sa[l]);
        float Z = 0.f, Zm = 0.f;
        for (int l = 0; l < S; ++l) { float e = expf(sa[l] - mx); Z += e; Zm += e * sm[l]; }
        float e = expf(sa[t] - mx);
        float a = (e / Z) * sm[t];
        sa2[t] = a / (Zm / Z + 1e-10f);
    }
    __syncthreads();
    float a0 = 0.f, a1 = 0.f;
    for (int l = 0; l < S; ++l) {
        const float* r = memb + ((size_t)b * S + l) * M;
        float a = sa2[l];
        a0 += a * r[t]; a1 += a * r[t + 256];
    }
    ctx[b * M + t] = a0; ctx[b * M + t + 256] = a1;
}

__global__ __launch_bounds__(256) void k_hid(
        const float* __restrict__ wctx, const float* __restrict__ sctx,
        const float* __restrict__ hlast, const float* __restrict__ W,
        const float* __restrict__ bias, float* __restrict__ hid) {
    __shared__ float cat[H3];
    int b = blockIdx.x, t = threadIdx.x;
    for (int i = t; i < 512; i += 256) {
        cat[i] = wctx[b * H + i];
        cat[512 + i] = sctx[b * H + i];
        cat[1024 + i] = hlast[b * H + i];
    }
    __syncthreads();
    for (int d = t; d < H; d += 256) {
        const float4* w = (const float4*)(W + (size_t)d * H3);
        float a = bias[d];
#pragma unroll 8
        for (int k = 0; k < H3 / 4; ++k) {
            float4 u = w[k];
            a += u.x * cat[4 * k] + u.y * cat[4 * k + 1] + u.z * cat[4 * k + 2] + u.w * cat[4 * k + 3];
        }
        hid[b * H + d] = a;
    }
}

__global__ void k_pgen(const float* __restrict__ wctx, const float* __restrict__ sctx,
                       const float* __restrict__ hlast, const float* __restrict__ yemb,
                       const float* __restrict__ pw, const float* __restrict__ pb,
                       float* __restrict__ pg) {
    int b = blockIdx.x, t = threadIdx.x;  // 64 threads (1 wave)
    float s = 0.f;
    for (int i = t; i < EMB + H + 2 * M; i += 64) {
        float x = (i < 512) ? wctx[b * H + i]
                : (i < 1024) ? sctx[b * H + i - 512]
                : (i < 1536) ? hlast[b * H + i - 1024]
                             : yemb[b * EMB + i - 1536];
        s += x * pw[i];
    }
    for (int off = 32; off; off >>= 1) s += __shfl_xor(s, off);
    if (t == 0) pg[b] = 1.f / (1.f + expf(-(s + pb[0])));
}

// logits[b,v] = hid[b,:] @ vd2_w[v,:] + vd2_b[v]; 128b x 64v tile, K=512
__global__ __launch_bounds__(256) void k_logits(
        const float* __restrict__ hid, const float* __restrict__ W,
        const float* __restrict__ bias, float* __restrict__ out) {
    __shared__ float Hs[128][68];
    __shared__ float Ws[64][68];
    int t = threadIdx.x, tx = t & 15, ty = t >> 4;
    int vBase = blockIdx.x * 64;
    float acc[8][4];
#pragma unroll
    for (int i = 0; i < 8; ++i)
#pragma unroll
        for (int j = 0; j < 4; ++j) acc[i][j] = 0.f;

    for (int kc = 0; kc < H; kc += 64) {
        int lc = tx * 4;
#pragma unroll
        for (int i = 0; i < 8; ++i) {
            int r = ty + 16 * i;
            *(float4*)&Hs[r][lc] = *(const float4*)(hid + (size_t)r * H + kc + lc);
        }
#pragma unroll
        for (int i = 0; i < 4; ++i) {
            int r = ty + 16 * i;
            int v = vBase + r;
            float4 w = make_float4(0.f, 0.f, 0.f, 0.f);
            if (v < V) w = *(const float4*)(W + (size_t)v * H + kc + lc);
            *(float4*)&Ws[r][lc] = w;
        }
        __syncthreads();
#pragma unroll 2
        for (int kk = 0; kk < 64; kk += 4) {
            float4 fa[8], fb[4];
#pragma unroll
            for (int i = 0; i < 8; ++i) fa[i] = *(const float4*)&Hs[ty + 16 * i][kk];
#pragma unroll
            for (int j = 0; j < 4; ++j) fb[j] = *(const float4*)&Ws[tx + 16 * j][kk];
#pragma unroll
            for (int i = 0; i < 8; ++i)
#pragma unroll
                for (int j = 0; j < 4; ++j)
                    acc[i][j] += fa[i].x * fb[j].x + fa[i].y * fb[j].y +
                                 fa[i].z * fb[j].z + fa[i].w * fb[j].w;
        }
        __syncthreads();
    }
#pragma unroll
    for (int i = 0; i < 8; ++i)
#pragma unroll
        for (int j = 0; j < 4; ++j) {
            int v = vBase + tx + 16 * j;
            if (v < V) out[(size_t)(ty + 16 * i) * V + v] = acc[i][j] + bias[v];
        }
}

__global__ __launch_bounds__(1024) void k_vreduce(
        const float* __restrict__ logits, float* __restrict__ rmax, float* __restrict__ rsum) {
    __shared__ float red[64];
    int b = blockIdx.x, t = threadIdx.x;
    const float4* row = (const float4*)(logits + (size_t)b * V);
    float mx = -1e30f;
    for (int i = t; i < V / 4; i += 1024) {
        float4 x = row[i];
        mx = fmaxf(fmaxf(mx, x.x), fmaxf(fmaxf(x.y, x.z), x.w));
    }
    for (int off = 32; off; off >>= 1) mx = fmaxf(mx, __shfl_xor(mx, off));
    if ((t & 63) == 0) red[t >> 6] = mx;
    __syncthreads();
    if (t < 16) {
        float m2 = red[t];
        for (int off = 8; off; off >>= 1) m2 = fmaxf(m2, __shfl_xor(m2, off, 16));
        if (t == 0) red[32] = m2;
    }
    __syncthreads();
    mx = red[32];
    float sm = 0.f;
    for (int i = t; i < V / 4; i += 1024) {
        float4 x = row[i];
        sm += expf(x.x - mx) + expf(x.y - mx) + expf(x.z - mx) + expf(x.w - mx);
    }
    for (int off = 32; off; off >>= 1) sm += __shfl_xor(sm, off);
    __syncthreads();
    if ((t & 63) == 0) red[t >> 6] = sm;
    __syncthreads();
    if (t < 16) {
        float s2 = red[t];
        for (int off = 8; off; off >>= 1) s2 += __shfl_xor(s2, off, 16);
        if (t == 0) { rmax[b] = mx; rsum[b] = s2; }
    }
}

__global__ void k_final(const float* __restrict__ logits, const float* __restrict__ rmax,
                        const float* __restrict__ rsum, const float* __restrict__ pgen,
                        float* __restrict__ fd) {
    int b = blockIdx.y;
    int col = blockIdx.x * 256 + threadIdx.x;
    if (col >= VO) return;
    float v = 0.f;
    if (col < V) v = pgen[b] * expf(logits[(size_t)b * V + col] - rmax[b]) / rsum[b];
    fd[(size_t)b * VO + col] = v;
}

__global__ void k_scatter(const int* __restrict__ oov, const float* __restrict__ wattn,
                          const float* __restrict__ pgen, float* __restrict__ fd) {
    int i = blockIdx.x * 256 + threadIdx.x;  // < B*L
    int b = i / L;
    float w = (1.f - pgen[b]) * wattn[i];
    atomicAdd(&fd[(size_t)b * VO + oov[i]], w);
}

extern "C" void kernel_launch(void* const* d_in, const int* in_sizes, int n_in,
                              void* d_out, int out_size, void* d_ws, size_t ws_size,
                              hipStream_t stream) {
    const float* h     = (const float*)d_in[0];
    const float* wmb   = (const float*)d_in[1];
    const float* smb   = (const float*)d_in[2];
    const float* wmask = (const float*)d_in[3];
    const float* smask = (const float*)d_in[4];
    const float* cov   = (const float*)d_in[5];
    const float* emb   = (const float*)d_in[6];
    const float* Wih   = (const float*)d_in[7];
    const float* Whh   = (const float*)d_in[8];
    const float* bih   = (const float*)d_in[9];
    const float* bhh   = (const float*)d_in[10];
    const float* Wmpw  = (const float*)d_in[11];
    const float* Wdpw  = (const float*)d_in[12];
    const float* bdpw  = (const float*)d_in[13];
    const float* vw    = (const float*)d_in[14];
    const float* covp  = (const float*)d_in[15];
    const float* Wmps  = (const float*)d_in[16];
    const float* Wdps  = (const float*)d_in[17];
    const float* bdps  = (const float*)d_in[18];
    const float* vs    = (const float*)d_in[19];
    const float* pw    = (const float*)d_in[20];
    const float* pb    = (const float*)d_in[21];
    const float* vd1w  = (const float*)d_in[22];
    const float* vd1b  = (const float*)d_in[23];
    const float* vd2w  = (const float*)d_in[24];
    const float* vd2b  = (const float*)d_in[25];
    const int*   y     = (const int*)d_in[26];
    const int*   oov   = (const int*)d_in[27];

    float* out   = (float*)d_out;
    float* fd    = out;
    float* hnext = out + O_HN;
    float* wctx  = out + O_WCTX;
    float* wattn = out + O_WATTN;
    float* pgen  = out + O_PGEN;
    float* wcov  = out + O_WCOV;

    float* ws     = (float*)d_ws;
    float* yemb   = ws;
    float* gi     = yemb + B * EMB;
    float* gh     = gi + B * H3;
    float* dpw    = gh + B * H3;
    float* dps    = dpw + B * H;
    float* wscore = dps + B * H;
    float* sscore = wscore + B * L;
    float* sctx   = sscore + B * S;
    float* hid    = sctx + B * M;
    float* logits = hid + B * H;
    float* rmax   = logits + (size_t)B * V;
    float* rsum   = rmax + B;

    k_zero<<<dim3((B * L + 255) / 256), 256, 0, stream>>>(wscore, sscore);
    k_gru_mm<<<B, 256, 0, stream>>>(emb, y, h, Wih, Whh, bih, bhh, yemb, gi, gh);
    k_gru_gates<<<(B * H) / 256, 256, 0, stream>>>(gi, gh, h, hnext);
    k_dec_proj<<<B, 256, 0, stream>>>(hnext, Wdpw, bdpw, Wdps, bdps, dpw, dps);
    k_feat<true><<<dim3(4, (B * L) / 64), 256, 0, stream>>>(wmb, Wmpw, dpw, cov, covp, vw, wscore, L);
    k_feat<false><<<dim3(4, (B * S) / 64), 256, 0, stream>>>(smb, Wmps, dps, nullptr, nullptr, vs, sscore, S);
    k_smax_word<<<B, 256, 0, stream>>>(wscore, wmask, cov, wattn, wcov);
    k_ctx_word<<<B, 128, 0, stream>>>(wattn, wmb, wctx);
    k_sent<<<B, 256, 0, stream>>>(sscore, smask, smb, sctx);
    k_hid<<<B, 256, 0, stream>>>(wctx, sctx, hnext, vd1w, vd1b, hid);
    k_pgen<<<B, 64, 0, stream>>>(wctx, sctx, hnext, yemb, pw, pb, pgen);
    k_logits<<<(V + 63) / 64, 256, 0, stream>>>(hid, vd2w, vd2b, logits);
    k_vreduce<<<B, 1024, 0, stream>>>(logits, rmax, rsum);
    k_final<<<dim3((VO + 255) / 256, B), 256, 0, stream>>>(logits, rmax, rsum, pgen, fd);
    k_scatter<<<(B * L) / 256, 256, 0, stream>>>(oov, wattn, pgen, fd);
}

// Round 2
// 576.892 us; speedup vs baseline: 1.7065x; 1.7065x over previous
//
#include <hip/hip_runtime.h>
#include <math.h>

#define B 128
#define L 400
#define S 30
#define V 50000
#define EMB 128
#define H 512
#define M 512
#define OOV 30
#define H3 1536
#define VO (V + OOV)

// ---- output layout (floats) ----
#define O_HN    (B * VO)
#define O_WCTX  (O_HN + B * H)
#define O_WATTN (O_WCTX + B * M)
#define O_PGEN  (O_WATTN + B * L)
#define O_WCOV  (O_PGEN + B)

typedef short bf16x8 __attribute__((ext_vector_type(8)));
typedef float f32x4 __attribute__((ext_vector_type(4)));

__global__ void k_zero(float* wscore, float* sscore) {
    int i = blockIdx.x * 256 + threadIdx.x;
    if (i < B * L) wscore[i] = 0.f;
    if (i < B * S) sscore[i] = 0.f;
}

// gi = y_emb @ Wih^T + bih ; gh = h @ Whh^T + bhh   (one block per b)
__global__ __launch_bounds__(256) void k_gru_mm(
        const float* __restrict__ emb, const int* __restrict__ y,
        const float* __restrict__ h,
        const float* __restrict__ Wih, const float* __restrict__ Whh,
        const float* __restrict__ bih, const float* __restrict__ bhh,
        float* __restrict__ yemb, float* __restrict__ gi, float* __restrict__ gh) {
    __shared__ float se[EMB];
    __shared__ float sh[H];
    int b = blockIdx.x, t = threadIdx.x;
    int yb = y[b];
    if (t < EMB) { float v = emb[(size_t)yb * EMB + t]; se[t] = v; yemb[b * EMB + t] = v; }
    sh[t] = h[b * H + t];
    sh[t + 256] = h[b * H + t + 256];
    __syncthreads();
    for (int j = t; j < H3; j += 256) {
        const float4* wi = (const float4*)(Wih + (size_t)j * EMB);
        float ai = bih[j];
#pragma unroll 8
        for (int k = 0; k < EMB / 4; ++k) {
            float4 w = wi[k];
            ai += w.x * se[4 * k] + w.y * se[4 * k + 1] + w.z * se[4 * k + 2] + w.w * se[4 * k + 3];
        }
        gi[b * H3 + j] = ai;
        const float4* wh = (const float4*)(Whh + (size_t)j * H);
        float ah = bhh[j];
#pragma unroll 8
        for (int k = 0; k < H / 4; ++k) {
            float4 w = wh[k];
            ah += w.x * sh[4 * k] + w.y * sh[4 * k + 1] + w.z * sh[4 * k + 2] + w.w * sh[4 * k + 3];
        }
        gh[b * H3 + j] = ah;
    }
}

__global__ void k_gru_gates(const float* __restrict__ gi, const float* __restrict__ gh,
                            const float* __restrict__ h, float* __restrict__ hnext) {
    int i = blockIdx.x * 256 + threadIdx.x;  // b*H + k
    int b = i >> 9, k = i & 511;
    float ir = gi[b * H3 + k], iz = gi[b * H3 + H + k], inn = gi[b * H3 + 2 * H + k];
    float hr = gh[b * H3 + k], hz = gh[b * H3 + H + k], hn = gh[b * H3 + 2 * H + k];
    float r = 1.f / (1.f + expf(-(ir + hr)));
    float z = 1.f / (1.f + expf(-(iz + hz)));
    float n = tanhf(inn + r * hn);
    hnext[i] = (1.f - z) * n + z * h[i];
}

__global__ __launch_bounds__(256) void k_dec_proj(
        const float* __restrict__ hlast,
        const float* __restrict__ Ww, const float* __restrict__ bw,
        const float* __restrict__ Ws, const float* __restrict__ bs,
        float* __restrict__ dpw, float* __restrict__ dps) {
    __shared__ float sh[H];
    int b = blockIdx.x, t = threadIdx.x;
    sh[t] = hlast[b * H + t]; sh[t + 256] = hlast[b * H + t + 256];
    __syncthreads();
    for (int d = t; d < H; d += 256) {
        const float4* w1 = (const float4*)(Ww + (size_t)d * H);
        const float4* w2 = (const float4*)(Ws + (size_t)d * H);
        float a1 = bw[d], a2 = bs[d];
#pragma unroll 8
        for (int k = 0; k < H / 4; ++k) {
            float4 u = w1[k]; float4 v = w2[k];
            float s0 = sh[4 * k], s1 = sh[4 * k + 1], s2 = sh[4 * k + 2], s3 = sh[4 * k + 3];
            a1 += u.x * s0 + u.y * s1 + u.z * s2 + u.w * s3;
            a2 += v.x * s0 + v.y * s1 + v.z * s2 + v.w * s3;
        }
        dpw[b * H + d] = a1; dps[b * H + d] = a2;
    }
}

// RNE fp32 -> bf16 pack of two values into one u32
__device__ __forceinline__ unsigned cvt2(float lo, float hi) {
    unsigned ul = __builtin_bit_cast(unsigned, lo);
    unsigned uh = __builtin_bit_cast(unsigned, hi);
    ul = (ul + 0x7FFFu + ((ul >> 16) & 1u)) >> 16;
    uh = (uh + 0x7FFFu + ((uh >> 16) & 1u)) >> 16;
    return ul | (uh << 16);
}

// stage a 128-row x 64-col fp32 tile -> bf16 LDS [128][72] (padded: 144B row stride)
__device__ __forceinline__ void stage_tile(const float* __restrict__ src, int rmax,
                                           int t, short dst[128][72]) {
    int col = (t & 7) * 8;   // 8 floats per thread per row-chunk
    int r0 = t >> 3;         // 32 rows per pass
#pragma unroll
    for (int i = 0; i < 4; ++i) {
        int r = r0 + i * 32;
        int rr = r < rmax ? r : rmax;
        const float* p = src + (size_t)rr * 512 + col;
        float4 a = *(const float4*)p;
        float4 c = *(const float4*)(p + 4);
        uint4 w;
        w.x = cvt2(a.x, a.y); w.y = cvt2(a.z, a.w);
        w.z = cvt2(c.x, c.y); w.w = cvt2(c.z, c.w);
        *(uint4*)&dst[r][col] = w;
    }
}

// C[m,n] = A[m,:] . B[n,:]  (K=512), tile 128x128, 4 waves of 64x64.
// EPI 0: word feat (cov) -> score atomics; EPI 1: sent feat -> score atomics;
// EPI 2: logits -> out[m*V+n] = acc + bias[n]
template <int EPI, int LR>
__global__ __launch_bounds__(256, 2) void k_gemm(
        const float* __restrict__ Ap, const float* __restrict__ Bp,
        const float* __restrict__ dproj, const float* __restrict__ cov,
        const float* __restrict__ covp, const float* __restrict__ vvec,
        const float* __restrict__ bias, float* __restrict__ outp, int Nlim) {
    __shared__ short As[128][72];
    __shared__ short Bs[128][72];
    int t = threadIdx.x;
    int lane = t & 63, wv = t >> 6;
    int wr = wv >> 1, wc = wv & 1;
    int l15 = lane & 15, l4 = lane >> 4;
    int mBase = blockIdx.y * 128;
    int nBase = blockIdx.x * 128;

    const float* Asrc = Ap + (size_t)mBase * 512;
    const float* Bsrc = Bp + (size_t)nBase * 512;
    int brmax = Nlim - 1 - nBase; if (brmax > 127) brmax = 127;

    f32x4 acc[4][4] = {};

    for (int kc = 0; kc < 512; kc += 64) {
        stage_tile(Asrc + kc, 127, t, As);
        stage_tile(Bsrc + kc, brmax, t, Bs);
        __syncthreads();
#pragma unroll
        for (int kk = 0; kk < 2; ++kk) {
            bf16x8 af[4], bq[4];
#pragma unroll
            for (int i = 0; i < 4; ++i)
                af[i] = *(const bf16x8*)&As[wr * 64 + i * 16 + l15][kk * 32 + l4 * 8];
#pragma unroll
            for (int j = 0; j < 4; ++j)
                bq[j] = *(const bf16x8*)&Bs[wc * 64 + j * 16 + l15][kk * 32 + l4 * 8];
#pragma unroll
            for (int i = 0; i < 4; ++i)
#pragma unroll
                for (int j = 0; j < 4; ++j)
                    acc[i][j] = __builtin_amdgcn_mfma_f32_16x16x32_bf16(
                        af[i], bq[j], acc[i][j], 0, 0, 0);
        }
        __syncthreads();
    }

    if (EPI <= 1) {
        int dB = nBase + wc * 64;
        float vv[4], cp[4];
#pragma unroll
        for (int j = 0; j < 4; ++j) {
            int d = dB + j * 16 + l15;
            vv[j] = vvec[d];
            cp[j] = (EPI == 0) ? covp[d] : 0.f;
        }
#pragma unroll
        for (int i = 0; i < 4; ++i) {
#pragma unroll
            for (int r = 0; r < 4; ++r) {
                int row = mBase + wr * 64 + i * 16 + l4 * 4 + r;
                int b = row / LR;
                float cv = (EPI == 0) ? cov[row] : 0.f;
                float s = 0.f;
#pragma unroll
                for (int j = 0; j < 4; ++j) {
                    int d = dB + j * 16 + l15;
                    float f = acc[i][j][r] + dproj[b * H + d];
                    if (EPI == 0) f += cv * cp[j];
                    s += vv[j] * tanhf(f);
                }
                s += __shfl_xor(s, 8, 16);
                s += __shfl_xor(s, 4, 16);
                s += __shfl_xor(s, 2, 16);
                s += __shfl_xor(s, 1, 16);
                if (l15 == 0) atomicAdd(&outp[row], s);
            }
        }
    } else {
#pragma unroll
        for (int i = 0; i < 4; ++i) {
#pragma unroll
            for (int r = 0; r < 4; ++r) {
                int row = mBase + wr * 64 + i * 16 + l4 * 4 + r;  // b index
#pragma unroll
                for (int j = 0; j < 4; ++j) {
                    int v = nBase + wc * 64 + j * 16 + l15;
                    if (v < Nlim)
                        outp[(size_t)row * V + v] = acc[i][j][r] + bias[v];
                }
            }
        }
    }
}

__global__ __launch_bounds__(256) void k_smax_word(
        const float* __restrict__ score, const float* __restrict__ mask,
        const float* __restrict__ cov, float* __restrict__ attn_out,
        float* __restrict__ cov_out) {
    __shared__ float sc[L];
    __shared__ float red[4];
    int b = blockIdx.x, t = threadIdx.x;
    float mx = -1e30f;
    for (int l = t; l < L; l += 256) { float s = score[b * L + l]; sc[l] = s; mx = fmaxf(mx, s); }
    for (int off = 32; off; off >>= 1) mx = fmaxf(mx, __shfl_xor(mx, off));
    if ((t & 63) == 0) red[t >> 6] = mx;
    __syncthreads();
    mx = fmaxf(fmaxf(red[0], red[1]), fmaxf(red[2], red[3]));
    __syncthreads();
    float sm = 0.f;
    for (int l = t; l < L; l += 256) { float e = expf(sc[l] - mx); sc[l] = e; sm += e; }
    for (int off = 32; off; off >>= 1) sm += __shfl_xor(sm, off);
    if ((t & 63) == 0) red[t >> 6] = sm;
    __syncthreads();
    float Z = red[0] + red[1] + red[2] + red[3];
    __syncthreads();
    float sm2 = 0.f;
    for (int l = t; l < L; l += 256) {
        float a = (sc[l] / Z) * mask[b * L + l];
        sc[l] = a; sm2 += a;
    }
    for (int off = 32; off; off >>= 1) sm2 += __shfl_xor(sm2, off);
    if ((t & 63) == 0) red[t >> 6] = sm2;
    __syncthreads();
    float Zm = red[0] + red[1] + red[2] + red[3] + 1e-10f;
    for (int l = t; l < L; l += 256) {
        float a = sc[l] / Zm;
        attn_out[b * L + l] = a;
        cov_out[b * L + l] = cov[b * L + l] + a;
    }
}

__global__ __launch_bounds__(128) void k_ctx_word(
        const float* __restrict__ attn, const float* __restrict__ memb,
        float* __restrict__ ctx) {
    __shared__ float sa[L];
    int b = blockIdx.x, t = threadIdx.x;  // 128 threads, float4 each
    for (int l = t; l < L; l += 128) sa[l] = attn[b * L + l];
    __syncthreads();
    float4 acc = make_float4(0.f, 0.f, 0.f, 0.f);
    for (int l = 0; l < L; ++l) {
        float4 m = ((const float4*)(memb + ((size_t)b * L + l) * M))[t];
        float a = sa[l];
        acc.x += a * m.x; acc.y += a * m.y; acc.z += a * m.z; acc.w += a * m.w;
    }
    ((float4*)(ctx + b * M))[t] = acc;
}

__global__ __launch_bounds__(256) void k_sent(
        const float* __restrict__ score, const float* __restrict__ mask,
        const float* __restrict__ memb, float* __restrict__ ctx) {
    __shared__ float sa[S], sa2[S], sm[S];
    int b = blockIdx.x, t = threadIdx.x;
    if (t < S) { sa[t] = score[b * S + t]; sm[t] = mask[b * S + t]; }
    __syncthreads();
    if (t < S) {
        float mx = -1e30f;
        for (int l = 0; l < S; ++l) mx = fmaxf(mx, sa[l]);
        float Z = 0.f, Zm = 0.f;
        for (int l = 0; l < S; ++l) { float e = expf(sa[l] - mx); Z += e; Zm += e * sm[l]; }
        float e = expf(sa[t] - mx);
        float a = (e / Z) * sm[t];
        sa2[t] = a / (Zm / Z + 1e-10f);
    }
    __syncthreads();
    float a0 = 0.f, a1 = 0.f;
    for (int l = 0; l < S; ++l) {
        const float* r = memb + ((size_t)b * S + l) * M;
        float a = sa2[l];
        a0 += a * r[t]; a1 += a * r[t + 256];
    }
    ctx[b * M + t] = a0; ctx[b * M + t + 256] = a1;
}

__global__ __launch_bounds__(256) void k_hid(
        const float* __restrict__ wctx, const float* __restrict__ sctx,
        const float* __restrict__ hlast, const float* __restrict__ W,
        const float* __restrict__ bias, float* __restrict__ hid) {
    __shared__ float cat[H3];
    int b = blockIdx.x, t = threadIdx.x;
    for (int i = t; i < 512; i += 256) {
        cat[i] = wctx[b * H + i];
        cat[512 + i] = sctx[b * H + i];
        cat[1024 + i] = hlast[b * H + i];
    }
    __syncthreads();
    for (int d = t; d < H; d += 256) {
        const float4* w = (const float4*)(W + (size_t)d * H3);
        float a = bias[d];
#pragma unroll 8
        for (int k = 0; k < H3 / 4; ++k) {
            float4 u = w[k];
            a += u.x * cat[4 * k] + u.y * cat[4 * k + 1] + u.z * cat[4 * k + 2] + u.w * cat[4 * k + 3];
        }
        hid[b * H + d] = a;
    }
}

__global__ void k_pgen(const float* __restrict__ wctx, const float* __restrict__ sctx,
                       const float* __restrict__ hlast, const float* __restrict__ yemb,
                       const float* __restrict__ pw, const float* __restrict__ pb,
                       float* __restrict__ pg) {
    int b = blockIdx.x, t = threadIdx.x;  // 64 threads (1 wave)
    float s = 0.f;
    for (int i = t; i < EMB + H + 2 * M; i += 64) {
        float x = (i < 512) ? wctx[b * H + i]
                : (i < 1024) ? sctx[b * H + i - 512]
                : (i < 1536) ? hlast[b * H + i - 1024]
                             : yemb[b * EMB + i - 1536];
        s += x * pw[i];
    }
    for (int off = 32; off; off >>= 1) s += __shfl_xor(s, off);
    if (t == 0) pg[b] = 1.f / (1.f + expf(-(s + pb[0])));
}

__global__ __launch_bounds__(1024) void k_vreduce(
        const float* __restrict__ logits, float* __restrict__ rmax, float* __restrict__ rsum) {
    __shared__ float red[64];
    int b = blockIdx.x, t = threadIdx.x;
    const float4* row = (const float4*)(logits + (size_t)b * V);
    float mx = -1e30f;
    for (int i = t; i < V / 4; i += 1024) {
        float4 x = row[i];
        mx = fmaxf(fmaxf(mx, x.x), fmaxf(fmaxf(x.y, x.z), x.w));
    }
    for (int off = 32; off; off >>= 1) mx = fmaxf(mx, __shfl_xor(mx, off));
    if ((t & 63) == 0) red[t >> 6] = mx;
    __syncthreads();
    if (t < 16) {
        float m2 = red[t];
        for (int off = 8; off; off >>= 1) m2 = fmaxf(m2, __shfl_xor(m2, off, 16));
        if (t == 0) red[32] = m2;
    }
    __syncthreads();
    mx = red[32];
    float sm = 0.f;
    for (int i = t; i < V / 4; i += 1024) {
        float4 x = row[i];
        sm += expf(x.x - mx) + expf(x.y - mx) + expf(x.z - mx) + expf(x.w - mx);
    }
    for (int off = 32; off; off >>= 1) sm += __shfl_xor(sm, off);
    __syncthreads();
    if ((t & 63) == 0) red[t >> 6] = sm;
    __syncthreads();
    if (t < 16) {
        float s2 = red[t];
        for (int off = 8; off; off >>= 1) s2 += __shfl_xor(s2, off, 16);
        if (t == 0) { rmax[b] = mx; rsum[b] = s2; }
    }
}

__global__ void k_final(const float* __restrict__ logits, const float* __restrict__ rmax,
                        const float* __restrict__ rsum, const float* __restrict__ pgen,
                        float* __restrict__ fd) {
    int b = blockIdx.y;
    int col = blockIdx.x * 256 + threadIdx.x;
    if (col >= VO) return;
    float v = 0.f;
    if (col < V) v = pgen[b] * expf(logits[(size_t)b * V + col] - rmax[b]) / rsum[b];
    fd[(size_t)b * VO + col] = v;
}

__global__ void k_scatter(const int* __restrict__ oov, const float* __restrict__ wattn,
                          const float* __restrict__ pgen, float* __restrict__ fd) {
    int i = blockIdx.x * 256 + threadIdx.x;  // < B*L
    int b = i / L;
    float w = (1.f - pgen[b]) * wattn[i];
    atomicAdd(&fd[(size_t)b * VO + oov[i]], w);
}

extern "C" void kernel_launch(void* const* d_in, const int* in_sizes, int n_in,
                              void* d_out, int out_size, void* d_ws, size_t ws_size,
                              hipStream_t stream) {
    const float* h     = (const float*)d_in[0];
    const float* wmb   = (const float*)d_in[1];
    const float* smb   = (const float*)d_in[2];
    const float* wmask = (const float*)d_in[3];
    const float* smask = (const float*)d_in[4];
    const float* cov   = (const float*)d_in[5];
    const float* emb   = (const float*)d_in[6];
    const float* Wih   = (const float*)d_in[7];
    const float* Whh   = (const float*)d_in[8];
    const float* bih   = (const float*)d_in[9];
    const float* bhh   = (const float*)d_in[10];
    const float* Wmpw  = (const float*)d_in[11];
    const float* Wdpw  = (const float*)d_in[12];
    const float* bdpw  = (const float*)d_in[13];
    const float* vw    = (const float*)d_in[14];
    const float* covp  = (const float*)d_in[15];
    const float* Wmps  = (const float*)d_in[16];
    const float* Wdps  = (const float*)d_in[17];
    const float* bdps  = (const float*)d_in[18];
    const float* vs    = (const float*)d_in[19];
    const float* pw    = (const float*)d_in[20];
    const float* pb    = (const float*)d_in[21];
    const float* vd1w  = (const float*)d_in[22];
    const float* vd1b  = (const float*)d_in[23];
    const float* vd2w  = (const float*)d_in[24];
    const float* vd2b  = (const float*)d_in[25];
    const int*   y     = (const int*)d_in[26];
    const int*   oov   = (const int*)d_in[27];

    float* out   = (float*)d_out;
    float* fd    = out;
    float* hnext = out + O_HN;
    float* wctx  = out + O_WCTX;
    float* wattn = out + O_WATTN;
    float* pgen  = out + O_PGEN;
    float* wcov  = out + O_WCOV;

    float* ws     = (float*)d_ws;
    float* yemb   = ws;
    float* gi     = yemb + B * EMB;
    float* gh     = gi + B * H3;
    float* dpw    = gh + B * H3;
    float* dps    = dpw + B * H;
    float* wscore = dps + B * H;
    float* sscore = wscore + B * L;
    float* sctx   = sscore + B * S;
    float* hid    = sctx + B * M;
    float* logits = hid + B * H;
    float* rmax   = logits + (size_t)B * V;
    float* rsum   = rmax + B;

    k_zero<<<dim3((B * L + 255) / 256), 256, 0, stream>>>(wscore, sscore);
    k_gru_mm<<<B, 256, 0, stream>>>(emb, y, h, Wih, Whh, bih, bhh, yemb, gi, gh);
    k_gru_gates<<<(B * H) / 256, 256, 0, stream>>>(gi, gh, h, hnext);
    k_dec_proj<<<B, 256, 0, stream>>>(hnext, Wdpw, bdpw, Wdps, bdps, dpw, dps);
    // word feat: rows = B*L = 51200, N = H = 512
    k_gemm<0, L><<<dim3(H / 128, (B * L) / 128), 256, 0, stream>>>(
        wmb, Wmpw, dpw, cov, covp, vw, nullptr, wscore, H);
    // sent feat: rows = B*S = 3840, N = H = 512
    k_gemm<1, S><<<dim3(H / 128, (B * S) / 128), 256, 0, stream>>>(
        smb, Wmps, dps, nullptr, nullptr, vs, nullptr, sscore, H);
    k_smax_word<<<B, 256, 0, stream>>>(wscore, wmask, cov, wattn, wcov);
    k_ctx_word<<<B, 128, 0, stream>>>(wattn, wmb, wctx);
    k_sent<<<B, 256, 0, stream>>>(sscore, smask, smb, sctx);
    k_hid<<<B, 256, 0, stream>>>(wctx, sctx, hnext, vd1w, vd1b, hid);
    k_pgen<<<B, 64, 0, stream>>>(wctx, sctx, hnext, yemb, pw, pb, pgen);
    // logits: M = B = 128 rows, N = V
    k_gemm<2, 1><<<dim3((V + 127) / 128, 1), 256, 0, stream>>>(
        hid, vd2w, nullptr, nullptr, nullptr, nullptr, vd2b, logits, V);
    k_vreduce<<<B, 1024, 0, stream>>>(logits, rmax, rsum);
    k_final<<<dim3((VO + 255) / 256, B), 256, 0, stream>>>(logits, rmax, rsum, pgen, fd);
    k_scatter<<<(B * L) / 256, 256, 0, stream>>>(oov, wattn, pgen, fd);
}

// Round 4
// 435.210 us; speedup vs baseline: 2.2621x; 1.3255x over previous
//
#include <hip/hip_runtime.h>
#include <hip/hip_bf16.h>
#include <math.h>

#define B 128
#define L 400
#define S 30
#define V 50000
#define EMB 128
#define H 512
#define M 512
#define OOV 30
#define H3 1536
#define VO (V + OOV)

// ---- output layout (floats) ----
#define O_HN    (B * VO)
#define O_WCTX  (O_HN + B * H)
#define O_WATTN (O_WCTX + B * M)
#define O_PGEN  (O_WATTN + B * L)
#define O_WCOV  (O_PGEN + B)

typedef short bf16x8 __attribute__((ext_vector_type(8)));
typedef float f32x4 __attribute__((ext_vector_type(4)));

__device__ __forceinline__ unsigned pk2(float a, float b) {
    union { __hip_bfloat162 h; unsigned u; } cv;
    cv.h = __float22bfloat162_rn(make_float2(a, b));
    return cv.u;
}

__device__ __forceinline__ float fast_tanh(float x) {
    float e = __expf(2.f * x);
    return 1.f - 2.f * __builtin_amdgcn_rcpf(e + 1.f);
}

__global__ void k_zero(float* wscore, float* sscore) {
    int i = blockIdx.x * 256 + threadIdx.x;
    if (i < B * L) wscore[i] = 0.f;
    if (i < B * S) sscore[i] = 0.f;
}

// convert the 7 reused weight matrices fp32 -> bf16 (2048 elems / block)
__global__ void k_cvtw(const float* __restrict__ wih, const float* __restrict__ whh,
                       const float* __restrict__ wdpw, const float* __restrict__ wdps,
                       const float* __restrict__ wmpw, const float* __restrict__ wmps,
                       const float* __restrict__ v1,
                       short* o_ih, short* o_hh, short* o_dpw, short* o_dps,
                       short* o_mpw, short* o_mps, short* o_v1) {
    int bb = blockIdx.x;
    const float* src; short* dst;
    if      (bb < 96)  { src = wih;  dst = o_ih; }
    else if (bb < 480) { src = whh;  dst = o_hh;  bb -= 96; }
    else if (bb < 608) { src = wdpw; dst = o_dpw; bb -= 480; }
    else if (bb < 736) { src = wdps; dst = o_dps; bb -= 608; }
    else if (bb < 864) { src = wmpw; dst = o_mpw; bb -= 736; }
    else if (bb < 992) { src = wmps; dst = o_mps; bb -= 864; }
    else               { src = v1;   dst = o_v1;  bb -= 992; }
    size_t i = (size_t)bb * 2048 + threadIdx.x * 8;
    float4 a = *(const float4*)(src + i);
    float4 c = *(const float4*)(src + i + 4);
    uint4 w;
    w.x = pk2(a.x, a.y); w.y = pk2(a.z, a.w);
    w.z = pk2(c.x, c.y); w.w = pk2(c.z, c.w);
    *(uint4*)(dst + i) = w;
}

__global__ void k_emb(const float* __restrict__ emb, const int* __restrict__ y,
                      float* __restrict__ yemb) {
    int i = blockIdx.x * 256 + threadIdx.x;  // B*EMB
    int b = i >> 7, e = i & 127;
    yemb[i] = emb[(size_t)y[b] * EMB + e];
}

// stage 128 rows x 64 cols fp32 -> bf16 LDS [128][72] (144B row stride)
__device__ __forceinline__ void stage_a(const float* __restrict__ src, int SK, int rmax,
                                        int t, short dst[128][72]) {
    int col = (t & 7) * 8;
    int r0 = t >> 3;
#pragma unroll
    for (int i = 0; i < 4; ++i) {
        int r = r0 + i * 32;
        int rr = r < rmax ? r : rmax;
        const float* p = src + (size_t)rr * SK + col;
        float4 a = *(const float4*)p;
        float4 c = *(const float4*)(p + 4);
        uint4 w;
        w.x = pk2(a.x, a.y); w.y = pk2(a.z, a.w);
        w.z = pk2(c.x, c.y); w.w = pk2(c.z, c.w);
        *(uint4*)&dst[r][col] = w;
    }
}

// stage 128 rows x 64 cols of bf16 source into LDS [128][72]
__device__ __forceinline__ void stage_b128bf(const short* __restrict__ src, int K,
                                             int t, short dst[128][72]) {
    int col = (t & 7) * 8;
    int r0 = t >> 3;
#pragma unroll
    for (int i = 0; i < 4; ++i) {
        int r = r0 + i * 32;
        *(bf16x8*)&dst[r][col] = *(const bf16x8*)(src + (size_t)r * K + col);
    }
}

// stage 256 rows x 64 cols of bf16 source into LDS [256][72]
__device__ __forceinline__ void stage_b256bf(const short* __restrict__ src, int K,
                                             int t, short dst[256][72]) {
    int col = (t & 7) * 8;
    int r0 = t >> 3;
#pragma unroll
    for (int i = 0; i < 8; ++i) {
        int r = r0 + i * 32;
        *(bf16x8*)&dst[r][col] = *(const bf16x8*)(src + (size_t)r * K + col);
    }
}

// ---------- generic M=128 GEMM: C[128,N] = A[128,K] @ Bw[N,K]^T + bias ----------
// BF16B: B operand pre-converted bf16; else fp32 streamed with fused cvt.
template <bool BF16B>
__global__ __launch_bounds__(256, 2) void k_mm128(
        const float* __restrict__ Ap, const float* __restrict__ Bf,
        const short* __restrict__ Bbf, const float* __restrict__ bias,
        float* __restrict__ C, int K, int ldc, int Nlim) {
    __shared__ short As[128][72];
    __shared__ short Bs[128][72];
    int t = threadIdx.x, lane = t & 63, wv = t >> 6;
    int wr = wv >> 1, wc = wv & 1;
    int l15 = lane & 15, l4 = lane >> 4;
    int nBase = blockIdx.x * 128;
    int brmax = Nlim - 1 - nBase; if (brmax > 127) brmax = 127;

    f32x4 acc[4][4] = {};
    for (int kc = 0; kc < K; kc += 64) {
        stage_a(Ap + kc, K, 127, t, As);
        if (BF16B) stage_b128bf(Bbf + (size_t)nBase * K + kc, K, t, Bs);
        else       stage_a(Bf + (size_t)nBase * K + kc, K, brmax, t, Bs);
        __syncthreads();
#pragma unroll
        for (int kk = 0; kk < 2; ++kk) {
            bf16x8 af[4], bq[4];
#pragma unroll
            for (int i = 0; i < 4; ++i)
                af[i] = *(const bf16x8*)&As[wr * 64 + i * 16 + l15][kk * 32 + l4 * 8];
#pragma unroll
            for (int j = 0; j < 4; ++j)
                bq[j] = *(const bf16x8*)&Bs[wc * 64 + j * 16 + l15][kk * 32 + l4 * 8];
#pragma unroll
            for (int i = 0; i < 4; ++i)
#pragma unroll
                for (int j = 0; j < 4; ++j)
                    acc[i][j] = __builtin_amdgcn_mfma_f32_16x16x32_bf16(
                        af[i], bq[j], acc[i][j], 0, 0, 0);
        }
        __syncthreads();
    }
#pragma unroll
    for (int i = 0; i < 4; ++i)
#pragma unroll
        for (int r = 0; r < 4; ++r) {
            int row = wr * 64 + i * 16 + l4 * 4 + r;
#pragma unroll
            for (int j = 0; j < 4; ++j) {
                int n = nBase + wc * 64 + j * 16 + l15;
                if (n < Nlim) C[(size_t)row * ldc + n] = acc[i][j][r] + bias[n];
            }
        }
}

// ---------- attention feature GEMM + tanh + v-dot ----------
// rows = B*LR (128/block), d-cols 256/block (grid.x = 2)
template <int EPI, int LR>
__global__ __launch_bounds__(256, 2) void k_feat(
        const float* __restrict__ Ap, const short* __restrict__ Bbf,
        const float* __restrict__ dproj, const float* __restrict__ cov,
        const float* __restrict__ covp, const float* __restrict__ vvec,
        float* __restrict__ outp) {
    __shared__ short As[128][72];
    __shared__ short Bs[256][72];
    int t = threadIdx.x, lane = t & 63, wv = t >> 6;
    int wr = wv >> 1, wc = wv & 1;
    int l15 = lane & 15, l4 = lane >> 4;
    int rowBase = blockIdx.y * 128;
    int nBase = blockIdx.x * 256;
    const float* Asrc = Ap + (size_t)rowBase * 512;
    const short* Bsrc = Bbf + (size_t)nBase * 512;

    f32x4 acc[4][8] = {};
    for (int kc = 0; kc < 512; kc += 64) {
        stage_a(Asrc + kc, 512, 127, t, As);
        stage_b256bf(Bsrc + kc, 512, t, Bs);
        __syncthreads();
#pragma unroll
        for (int kk = 0; kk < 2; ++kk) {
            bf16x8 af[4], bq[8];
#pragma unroll
            for (int i = 0; i < 4; ++i)
                af[i] = *(const bf16x8*)&As[wr * 64 + i * 16 + l15][kk * 32 + l4 * 8];
#pragma unroll
            for (int j = 0; j < 8; ++j)
                bq[j] = *(const bf16x8*)&Bs[wc * 128 + j * 16 + l15][kk * 32 + l4 * 8];
#pragma unroll
            for (int i = 0; i < 4; ++i)
#pragma unroll
                for (int j = 0; j < 8; ++j)
                    acc[i][j] = __builtin_amdgcn_mfma_f32_16x16x32_bf16(
                        af[i], bq[j], acc[i][j], 0, 0, 0);
        }
        __syncthreads();
    }
    int dB = nBase + wc * 128;
    float vv[8], cp[8];
#pragma unroll
    for (int j = 0; j < 8; ++j) {
        int d = dB + j * 16 + l15;
        vv[j] = vvec[d];
        cp[j] = (EPI == 0) ? covp[d] : 0.f;
    }
#pragma unroll
    for (int i = 0; i < 4; ++i) {
#pragma unroll
        for (int r = 0; r < 4; ++r) {
            int row = rowBase + wr * 64 + i * 16 + l4 * 4 + r;
            int b = row / LR;
            float cv = (EPI == 0) ? cov[row] : 0.f;
            float s = 0.f;
#pragma unroll
            for (int j = 0; j < 8; ++j) {
                int d = dB + j * 16 + l15;
                float f = acc[i][j][r] + dproj[b * H + d];
                if (EPI == 0) f += cv * cp[j];
                s += vv[j] * fast_tanh(f);
            }
            s += __shfl_xor(s, 8, 16);
            s += __shfl_xor(s, 4, 16);
            s += __shfl_xor(s, 2, 16);
            s += __shfl_xor(s, 1, 16);
            if (l15 == 0) atomicAdd(&outp[row], s);
        }
    }
}

__global__ void k_gates(const float* __restrict__ gi, const float* __restrict__ gh,
                        const float* __restrict__ h, float* __restrict__ hnext) {
    int i = blockIdx.x * 256 + threadIdx.x;  // b*H + k
    int b = i >> 9, k = i & 511;
    float ir = gi[b * H3 + k], iz = gi[b * H3 + H + k], inn = gi[b * H3 + 2 * H + k];
    float hr = gh[b * H3 + k], hz = gh[b * H3 + H + k], hn = gh[b * H3 + 2 * H + k];
    float r = 1.f / (1.f + __expf(-(ir + hr)));
    float z = 1.f / (1.f + __expf(-(iz + hz)));
    float n = fast_tanh(inn + r * hn);
    hnext[i] = (1.f - z) * n + z * h[i];
}

__global__ __launch_bounds__(256) void k_smax_word(
        const float* __restrict__ score, const float* __restrict__ mask,
        const float* __restrict__ cov, float* __restrict__ attn_out,
        float* __restrict__ cov_out) {
    __shared__ float sc[L];
    __shared__ float red[4];
    int b = blockIdx.x, t = threadIdx.x;
    float mx = -1e30f;
    for (int l = t; l < L; l += 256) { float s = score[b * L + l]; sc[l] = s; mx = fmaxf(mx, s); }
    for (int off = 32; off; off >>= 1) mx = fmaxf(mx, __shfl_xor(mx, off));
    if ((t & 63) == 0) red[t >> 6] = mx;
    __syncthreads();
    mx = fmaxf(fmaxf(red[0], red[1]), fmaxf(red[2], red[3]));
    __syncthreads();
    float sm = 0.f;
    for (int l = t; l < L; l += 256) { float e = __expf(sc[l] - mx); sc[l] = e; sm += e; }
    for (int off = 32; off; off >>= 1) sm += __shfl_xor(sm, off);
    if ((t & 63) == 0) red[t >> 6] = sm;
    __syncthreads();
    float Z = red[0] + red[1] + red[2] + red[3];
    __syncthreads();
    float sm2 = 0.f;
    for (int l = t; l < L; l += 256) {
        float a = (sc[l] / Z) * mask[b * L + l];
        sc[l] = a; sm2 += a;
    }
    for (int off = 32; off; off >>= 1) sm2 += __shfl_xor(sm2, off);
    if ((t & 63) == 0) red[t >> 6] = sm2;
    __syncthreads();
    float Zm = red[0] + red[1] + red[2] + red[3] + 1e-10f;
    for (int l = t; l < L; l += 256) {
        float a = sc[l] / Zm;
        attn_out[b * L + l] = a;
        cov_out[b * L + l] = cov[b * L + l] + a;
    }
}

// ctx partials: grid (4, B); block handles 100 L-rows, 512 cols (float2/thread)
__global__ __launch_bounds__(256) void k_ctx_part(
        const float* __restrict__ attn, const float* __restrict__ memb,
        float* __restrict__ ctxp) {
    __shared__ float sa[100];
    int b = blockIdx.y, ch = blockIdx.x, t = threadIdx.x;
    int l0 = ch * 100;
    if (t < 100) sa[t] = attn[b * L + l0 + t];
    __syncthreads();
    float ax = 0.f, ay = 0.f;
    const float* base = memb + ((size_t)b * L + l0) * M + t * 2;
#pragma unroll 4
    for (int l = 0; l < 100; ++l) {
        float2 m2 = *(const float2*)(base + (size_t)l * M);
        float a = sa[l];
        ax += a * m2.x; ay += a * m2.y;
    }
    float* o = ctxp + ((size_t)(ch * B + b)) * M + t * 2;
    o[0] = ax; o[1] = ay;
}

__global__ void k_ctx_red(const float* __restrict__ ctxp, float* __restrict__ ctx) {
    int j = blockIdx.x * 256 + threadIdx.x;  // B*M
    ctx[j] = ctxp[j] + ctxp[B * M + j] + ctxp[2 * B * M + j] + ctxp[3 * B * M + j];
}

__global__ __launch_bounds__(256) void k_sent(
        const float* __restrict__ score, const float* __restrict__ mask,
        const float* __restrict__ memb, float* __restrict__ ctx) {
    __shared__ float sa[S], sa2[S], sm[S];
    int b = blockIdx.x, t = threadIdx.x;
    if (t < S) { sa[t] = score[b * S + t]; sm[t] = mask[b * S + t]; }
    __syncthreads();
    if (t < S) {
        float mx = -1e30f;
        for (int l = 0; l < S; ++l) mx = fmaxf(mx, sa[l]);
        float Z = 0.f, Zm = 0.f;
        for (int l = 0; l < S; ++l) { float e = __expf(sa[l] - mx); Z += e; Zm += e * sm[l]; }
        float e = __expf(sa[t] - mx);
        float a = (e / Z) * sm[t];
        sa2[t] = a / (Zm / Z + 1e-10f);
    }
    __syncthreads();
    float a0 = 0.f, a1 = 0.f;
    for (int l = 0; l < S; ++l) {
        const float* r = memb + ((size_t)b * S + l) * M;
        float a = sa2[l];
        a0 += a * r[t]; a1 += a * r[t + 256];
    }
    ctx[b * M + t] = a0; ctx[b * M + t + 256] = a1;
}

__global__ void k_cat(const float* __restrict__ wctx, const float* __restrict__ sctx,
                      const float* __restrict__ hlast, float* __restrict__ cat) {
    int i = blockIdx.x * 256 + threadIdx.x;  // B*H3
    int b = i / H3, c = i - b * H3;
    float v = (c < 512) ? wctx[b * H + c]
            : (c < 1024) ? sctx[b * H + c - 512]
                         : hlast[b * H + c - 1024];
    cat[i] = v;
}

__global__ void k_pgen(const float* __restrict__ wctx, const float* __restrict__ sctx,
                       const float* __restrict__ hlast, const float* __restrict__ yemb,
                       const float* __restrict__ pw, const float* __restrict__ pb,
                       float* __restrict__ pg) {
    int b = blockIdx.x, t = threadIdx.x;  // 64 threads
    float s = 0.f;
    for (int i = t; i < EMB + H + 2 * M; i += 64) {
        float x = (i < 512) ? wctx[b * H + i]
                : (i < 1024) ? sctx[b * H + i - 512]
                : (i < 1536) ? hlast[b * H + i - 1024]
                             : yemb[b * EMB + i - 1536];
        s += x * pw[i];
    }
    for (int off = 32; off; off >>= 1) s += __shfl_xor(s, off);
    if (t == 0) pg[b] = 1.f / (1.f + __expf(-(s + pb[0])));
}

// fused vocab softmax + p_gen scale + OOV-tail zero; one block per b
__global__ __launch_bounds__(256) void k_smfinal(
        const float* __restrict__ logits, const float* __restrict__ pgen,
        float* __restrict__ fd) {
    __shared__ float wm[4], wsv[4];
    int b = blockIdx.x, t = threadIdx.x;
    const float4* row = (const float4*)(logits + (size_t)b * V);
    float m = -1e30f, s = 0.f;
    for (int i = t; i < V / 4; i += 256) {
        float4 x = row[i];
        float m4 = fmaxf(fmaxf(x.x, x.y), fmaxf(x.z, x.w));
        if (m4 > m) { s *= __expf(m - m4); m = m4; }
        s += __expf(x.x - m) + __expf(x.y - m) + __expf(x.z - m) + __expf(x.w - m);
    }
    for (int off = 32; off; off >>= 1) {
        float mo = __shfl_xor(m, off), so = __shfl_xor(s, off);
        float mn = fmaxf(m, mo);
        s = s * __expf(m - mn) + so * __expf(mo - mn);
        m = mn;
    }
    if ((t & 63) == 0) { wm[t >> 6] = m; wsv[t >> 6] = s; }
    __syncthreads();
    float M2 = fmaxf(fmaxf(wm[0], wm[1]), fmaxf(wm[2], wm[3]));
    float S2 = wsv[0] * __expf(wm[0] - M2) + wsv[1] * __expf(wm[1] - M2) +
               wsv[2] * __expf(wm[2] - M2) + wsv[3] * __expf(wm[3] - M2);
    float inv = pgen[b] / S2;
    float* outb = fd + (size_t)b * VO;
    for (int i = t; i < V / 4; i += 256) {
        float4 x = row[i];
        float2 lo = make_float2(inv * __expf(x.x - M2), inv * __expf(x.y - M2));
        float2 hi = make_float2(inv * __expf(x.z - M2), inv * __expf(x.w - M2));
        *(float2*)(outb + i * 4) = lo;
        *(float2*)(outb + i * 4 + 2) = hi;
    }
    if (t < VO - V) outb[V + t] = 0.f;
}

__global__ void k_scatter(const int* __restrict__ oov, const float* __restrict__ wattn,
                          const float* __restrict__ pgen, float* __restrict__ fd) {
    int i = blockIdx.x * 256 + threadIdx.x;  // < B*L
    int b = i / L;
    float w = (1.f - pgen[b]) * wattn[i];
    atomicAdd(&fd[(size_t)b * VO + oov[i]], w);
}

extern "C" void kernel_launch(void* const* d_in, const int* in_sizes, int n_in,
                              void* d_out, int out_size, void* d_ws, size_t ws_size,
                              hipStream_t stream) {
    const float* h     = (const float*)d_in[0];
    const float* wmb   = (const float*)d_in[1];
    const float* smb   = (const float*)d_in[2];
    const float* wmask = (const float*)d_in[3];
    const float* smask = (const float*)d_in[4];
    const float* cov   = (const float*)d_in[5];
    const float* emb   = (const float*)d_in[6];
    const float* Wih   = (const float*)d_in[7];
    const float* Whh   = (const float*)d_in[8];
    const float* bih   = (const float*)d_in[9];
    const float* bhh   = (const float*)d_in[10];
    const float* Wmpw  = (const float*)d_in[11];
    const float* Wdpw  = (const float*)d_in[12];
    const float* bdpw  = (const float*)d_in[13];
    const float* vw    = (const float*)d_in[14];
    const float* covp  = (const float*)d_in[15];
    const float* Wmps  = (const float*)d_in[16];
    const float* Wdps  = (const float*)d_in[17];
    const float* bdps  = (const float*)d_in[18];
    const float* vs    = (const float*)d_in[19];
    const float* pw    = (const float*)d_in[20];
    const float* pb    = (const float*)d_in[21];
    const float* vd1w  = (const float*)d_in[22];
    const float* vd1b  = (const float*)d_in[23];
    const float* vd2w  = (const float*)d_in[24];
    const float* vd2b  = (const float*)d_in[25];
    const int*   y     = (const int*)d_in[26];
    const int*   oov   = (const int*)d_in[27];

    float* out   = (float*)d_out;
    float* fd    = out;
    float* hnext = out + O_HN;
    float* wctx  = out + O_WCTX;
    float* wattn = out + O_WATTN;
    float* pgen  = out + O_PGEN;
    float* wcov  = out + O_WCOV;

    float* ws     = (float*)d_ws;
    float* yemb   = ws;                       // 16384
    float* gi     = yemb + B * EMB;           // 196608 (cat aliases)
    float* gh     = gi + B * H3;              // 196608
    float* dpw    = gh + B * H3;              // 65536
    float* dps    = dpw + B * H;              // 65536
    float* wscore = dps + B * H;              // 51200
    float* sscore = wscore + B * L;           // 3840
    float* sctx   = sscore + B * S;           // 65536
    float* hid    = sctx + B * M;             // 65536
    float* logits = hid + B * H;              // B*V (ctxp aliases)
    float* cat    = gi;
    float* ctxp   = logits;
    short* wb     = (short*)(logits + (size_t)B * V);
    short* wb_ih  = wb;                       // 1536*128
    short* wb_hh  = wb_ih + H3 * EMB;         // 1536*512
    short* wb_dpw = wb_hh + H3 * H;           // 512*512
    short* wb_dps = wb_dpw + H * H;
    short* wb_mpw = wb_dps + H * H;
    short* wb_mps = wb_mpw + H * M;
    short* wb_v1  = wb_mps + H * M;           // 512*1536

    k_zero<<<200, 256, 0, stream>>>(wscore, sscore);
    k_cvtw<<<1376, 256, 0, stream>>>(Wih, Whh, Wdpw, Wdps, Wmpw, Wmps, vd1w,
                                     wb_ih, wb_hh, wb_dpw, wb_dps, wb_mpw, wb_mps, wb_v1);
    k_emb<<<64, 256, 0, stream>>>(emb, y, yemb);
    k_mm128<true><<<12, 256, 0, stream>>>(yemb, nullptr, wb_ih, bih, gi, EMB, H3, H3);
    k_mm128<true><<<12, 256, 0, stream>>>(h, nullptr, wb_hh, bhh, gh, H, H3, H3);
    k_gates<<<256, 256, 0, stream>>>(gi, gh, h, hnext);
    k_mm128<true><<<4, 256, 0, stream>>>(hnext, nullptr, wb_dpw, bdpw, dpw, H, H, H);
    k_mm128<true><<<4, 256, 0, stream>>>(hnext, nullptr, wb_dps, bdps, dps, H, H, H);
    k_feat<0, L><<<dim3(2, (B * L) / 128), 256, 0, stream>>>(wmb, wb_mpw, dpw, cov, covp, vw, wscore);
    k_feat<1, S><<<dim3(2, (B * S) / 128), 256, 0, stream>>>(smb, wb_mps, dps, nullptr, nullptr, vs, sscore);
    k_smax_word<<<B, 256, 0, stream>>>(wscore, wmask, cov, wattn, wcov);
    k_ctx_part<<<dim3(4, B), 256, 0, stream>>>(wattn, wmb, ctxp);
    k_ctx_red<<<(B * M) / 256, 256, 0, stream>>>(ctxp, wctx);
    k_sent<<<B, 256, 0, stream>>>(sscore, smask, smb, sctx);
    k_cat<<<(B * H3) / 256, 256, 0, stream>>>(wctx, sctx, hnext, cat);
    k_mm128<true><<<4, 256, 0, stream>>>(cat, nullptr, wb_v1, vd1b, hid, H3, H, H);
    k_pgen<<<B, 64, 0, stream>>>(wctx, sctx, hnext, yemb, pw, pb, pgen);
    k_mm128<false><<<(V + 127) / 128, 256, 0, stream>>>(hid, vd2w, nullptr, vd2b, logits, H, V, V);
    k_smfinal<<<B, 256, 0, stream>>>(logits, pgen, fd);
    k_scatter<<<200, 256, 0, stream>>>(oov, wattn, pgen, fd);
}

// Round 5
// 236.306 us; speedup vs baseline: 4.1661x; 1.8417x over previous
//
#include <hip/hip_runtime.h>
#include <hip/hip_bf16.h>
#include <math.h>

#define B 128
#define L 400
#define S 30
#define V 50000
#define EMB 128
#define H 512
#define M 512
#define OOV 30
#define H3 1536
#define VO (V + OOV)

// ---- output layout (floats) ----
#define O_HN    (B * VO)
#define O_WCTX  (O_HN + B * H)
#define O_WATTN (O_WCTX + B * M)
#define O_PGEN  (O_WATTN + B * L)
#define O_WCOV  (O_PGEN + B)

typedef short bf16x8 __attribute__((ext_vector_type(8)));
typedef float f32x4 __attribute__((ext_vector_type(4)));

__device__ __forceinline__ unsigned pk2(float a, float b) {
    union { __hip_bfloat162 h; unsigned u; } cv;
    cv.h = __float22bfloat162_rn(make_float2(a, b));
    return cv.u;
}

__device__ __forceinline__ float fast_tanh(float x) {
    float e = __expf(2.f * x);
    return 1.f - 2.f * __builtin_amdgcn_rcpf(e + 1.f);
}

// ---- init: bias-broadcast C buffers, zero scores, gather y embedding ----
__global__ void k_init(const float* __restrict__ bih, const float* __restrict__ bhh,
                       const float* __restrict__ bdpw, const float* __restrict__ bdps,
                       const float* __restrict__ v1b, const float* __restrict__ emb,
                       const int* __restrict__ y,
                       float* gi, float* gh, float* dpw, float* dps, float* hid,
                       float* wscore, float* sscore, float* yemb) {
    int i = blockIdx.x * 256 + threadIdx.x;
    if (i < 196608) { gi[i] = bih[i % 1536]; return; }
    i -= 196608;
    if (i < 196608) { gh[i] = bhh[i % 1536]; return; }
    i -= 196608;
    if (i < 65536) { dpw[i] = bdpw[i & 511]; return; }
    i -= 65536;
    if (i < 65536) { dps[i] = bdps[i & 511]; return; }
    i -= 65536;
    if (i < 65536) { hid[i] = v1b[i & 511]; return; }
    i -= 65536;
    if (i < 51200) { wscore[i] = 0.f; return; }
    i -= 51200;
    if (i < 3840) { sscore[i] = 0.f; return; }
    i -= 3840;
    { int b = i >> 7, e = i & 127; yemb[i] = emb[(size_t)y[b] * EMB + e]; }
}

// convert the 7 reused weight matrices fp32 -> bf16 (2048 elems / block)
__global__ void k_cvtw(const float* __restrict__ wih, const float* __restrict__ whh,
                       const float* __restrict__ wdpw, const float* __restrict__ wdps,
                       const float* __restrict__ wmpw, const float* __restrict__ wmps,
                       const float* __restrict__ v1,
                       short* o_ih, short* o_hh, short* o_dpw, short* o_dps,
                       short* o_mpw, short* o_mps, short* o_v1) {
    int bb = blockIdx.x;
    const float* src; short* dst;
    if      (bb < 96)  { src = wih;  dst = o_ih; }
    else if (bb < 480) { src = whh;  dst = o_hh;  bb -= 96; }
    else if (bb < 608) { src = wdpw; dst = o_dpw; bb -= 480; }
    else if (bb < 736) { src = wdps; dst = o_dps; bb -= 608; }
    else if (bb < 864) { src = wmpw; dst = o_mpw; bb -= 736; }
    else if (bb < 992) { src = wmps; dst = o_mps; bb -= 864; }
    else               { src = v1;   dst = o_v1;  bb -= 992; }
    size_t i = (size_t)bb * 2048 + threadIdx.x * 8;
    float4 a = *(const float4*)(src + i);
    float4 c = *(const float4*)(src + i + 4);
    uint4 w;
    w.x = pk2(a.x, a.y); w.y = pk2(a.z, a.w);
    w.z = pk2(c.x, c.y); w.w = pk2(c.z, c.w);
    *(uint4*)(dst + i) = w;
}

// stage 128 rows x 64 cols fp32 -> bf16 LDS [128][72]
__device__ __forceinline__ void stage_a(const float* __restrict__ src, int SK, int rmax,
                                        int t, short dst[128][72]) {
    int col = (t & 7) * 8;
    int r0 = t >> 3;
#pragma unroll
    for (int i = 0; i < 4; ++i) {
        int r = r0 + i * 32;
        int rr = r < rmax ? r : rmax;
        const float* p = src + (size_t)rr * SK + col;
        float4 a = *(const float4*)p;
        float4 c = *(const float4*)(p + 4);
        uint4 w;
        w.x = pk2(a.x, a.y); w.y = pk2(a.z, a.w);
        w.z = pk2(c.x, c.y); w.w = pk2(c.z, c.w);
        *(uint4*)&dst[r][col] = w;
    }
}

__device__ __forceinline__ void stage_b128bf(const short* __restrict__ src, int K,
                                             int t, short dst[128][72]) {
    int col = (t & 7) * 8;
    int r0 = t >> 3;
#pragma unroll
    for (int i = 0; i < 4; ++i) {
        int r = r0 + i * 32;
        *(bf16x8*)&dst[r][col] = *(const bf16x8*)(src + (size_t)r * K + col);
    }
}

__device__ __forceinline__ void stage_b256bf(const short* __restrict__ src, int K,
                                             int t, short dst[256][72]) {
    int col = (t & 7) * 8;
    int r0 = t >> 3;
#pragma unroll
    for (int i = 0; i < 8; ++i) {
        int r = r0 + i * 32;
        *(bf16x8*)&dst[r][col] = *(const bf16x8*)(src + (size_t)r * K + col);
    }
}

// ---------- split-K skinny GEMM (M=128): C += A @ Bw^T, atomics, 2 fused jobs ----------
__global__ __launch_bounds__(256, 2) void k_mmsk(
        const float* __restrict__ A0, const short* __restrict__ B0, float* __restrict__ C0,
        int K0, int NT0, int KB0,
        const float* __restrict__ A1, const short* __restrict__ B1, float* __restrict__ C1,
        int K1, int NT1, int KB1) {
    __shared__ short As[128][72];
    __shared__ short Bs[128][72];
    int t = threadIdx.x, lane = t & 63, wv = t >> 6;
    int wr = wv >> 1, wc = wv & 1;
    int l15 = lane & 15, l4 = lane >> 4;

    int bb = blockIdx.x;
    const float* A; const short* Bb; float* C; int K, NT, KB;
    if (bb < NT0 * KB0) { A = A0; Bb = B0; C = C0; K = K0; NT = NT0; KB = KB0; }
    else { bb -= NT0 * KB0; A = A1; Bb = B1; C = C1; K = K1; NT = NT1; KB = KB1; }
    int nIdx = bb % NT, kIdx = bb / NT;
    int ldc = NT * 128;
    int nBase = nIdx * 128;
    int KC = K / KB;
    int kLo = kIdx * KC, kHi = kLo + KC;

    f32x4 acc[4][4] = {};
    for (int kc = kLo; kc < kHi; kc += 64) {
        stage_a(A + kc, K, 127, t, As);
        stage_b128bf(Bb + (size_t)nBase * K + kc, K, t, Bs);
        __syncthreads();
#pragma unroll
        for (int kk = 0; kk < 2; ++kk) {
            bf16x8 af[4], bq[4];
#pragma unroll
            for (int i = 0; i < 4; ++i)
                af[i] = *(const bf16x8*)&As[wr * 64 + i * 16 + l15][kk * 32 + l4 * 8];
#pragma unroll
            for (int j = 0; j < 4; ++j)
                bq[j] = *(const bf16x8*)&Bs[wc * 64 + j * 16 + l15][kk * 32 + l4 * 8];
#pragma unroll
            for (int i = 0; i < 4; ++i)
#pragma unroll
                for (int j = 0; j < 4; ++j)
                    acc[i][j] = __builtin_amdgcn_mfma_f32_16x16x32_bf16(
                        af[i], bq[j], acc[i][j], 0, 0, 0);
        }
        __syncthreads();
    }
#pragma unroll
    for (int i = 0; i < 4; ++i)
#pragma unroll
        for (int r = 0; r < 4; ++r) {
            int row = wr * 64 + i * 16 + l4 * 4 + r;
#pragma unroll
            for (int j = 0; j < 4; ++j) {
                int n = nBase + wc * 64 + j * 16 + l15;
                atomicAdd(&C[(size_t)row * ldc + n], acc[i][j][r]);
            }
        }
}

// ---------- vocab logits GEMM: C[128,V] = hid @ vd2w^T + bias ----------
__global__ __launch_bounds__(256, 2) void k_mm128(
        const float* __restrict__ Ap, const float* __restrict__ Bf,
        const float* __restrict__ bias, float* __restrict__ C, int K, int ldc, int Nlim) {
    __shared__ short As[128][72];
    __shared__ short Bs[128][72];
    int t = threadIdx.x, lane = t & 63, wv = t >> 6;
    int wr = wv >> 1, wc = wv & 1;
    int l15 = lane & 15, l4 = lane >> 4;
    int nBase = blockIdx.x * 128;
    int brmax = Nlim - 1 - nBase; if (brmax > 127) brmax = 127;

    f32x4 acc[4][4] = {};
    for (int kc = 0; kc < K; kc += 64) {
        stage_a(Ap + kc, K, 127, t, As);
        stage_a(Bf + (size_t)nBase * K + kc, K, brmax, t, Bs);
        __syncthreads();
#pragma unroll
        for (int kk = 0; kk < 2; ++kk) {
            bf16x8 af[4], bq[4];
#pragma unroll
            for (int i = 0; i < 4; ++i)
                af[i] = *(const bf16x8*)&As[wr * 64 + i * 16 + l15][kk * 32 + l4 * 8];
#pragma unroll
            for (int j = 0; j < 4; ++j)
                bq[j] = *(const bf16x8*)&Bs[wc * 64 + j * 16 + l15][kk * 32 + l4 * 8];
#pragma unroll
            for (int i = 0; i < 4; ++i)
#pragma unroll
                for (int j = 0; j < 4; ++j)
                    acc[i][j] = __builtin_amdgcn_mfma_f32_16x16x32_bf16(
                        af[i], bq[j], acc[i][j], 0, 0, 0);
        }
        __syncthreads();
    }
#pragma unroll
    for (int i = 0; i < 4; ++i)
#pragma unroll
        for (int r = 0; r < 4; ++r) {
            int row = wr * 64 + i * 16 + l4 * 4 + r;
#pragma unroll
            for (int j = 0; j < 4; ++j) {
                int n = nBase + wc * 64 + j * 16 + l15;
                if (n < Nlim) C[(size_t)row * ldc + n] = acc[i][j][r] + bias[n];
            }
        }
}

// ---------- fused word+sent attention feature GEMM + tanh + v-dot ----------
__global__ __launch_bounds__(256, 2) void k_feat2(
        const float* __restrict__ wmb, const short* __restrict__ wbmpw,
        const float* __restrict__ dpw, const float* __restrict__ cov,
        const float* __restrict__ covp, const float* __restrict__ vw,
        float* __restrict__ wscore,
        const float* __restrict__ smb, const short* __restrict__ wbmps,
        const float* __restrict__ dps, const float* __restrict__ vs,
        float* __restrict__ sscore) {
    __shared__ short As[128][72];
    __shared__ short Bs[256][72];
    int t = threadIdx.x, lane = t & 63, wv = t >> 6;
    int wr = wv >> 1, wc = wv & 1;
    int l15 = lane & 15, l4 = lane >> 4;

    bool word = blockIdx.y < 400;
    const float* Ap; const short* Bbf; const float* dproj; const float* vvec; float* outp;
    int rowBase;
    if (word) { Ap = wmb; Bbf = wbmpw; dproj = dpw; vvec = vw; outp = wscore; rowBase = blockIdx.y * 128; }
    else      { Ap = smb; Bbf = wbmps; dproj = dps; vvec = vs; outp = sscore; rowBase = (blockIdx.y - 400) * 128; }
    int nBase = blockIdx.x * 256;
    const float* Asrc = Ap + (size_t)rowBase * 512;
    const short* Bsrc = Bbf + (size_t)nBase * 512;

    f32x4 acc[4][8] = {};
    for (int kc = 0; kc < 512; kc += 64) {
        stage_a(Asrc + kc, 512, 127, t, As);
        stage_b256bf(Bsrc + kc, 512, t, Bs);
        __syncthreads();
#pragma unroll
        for (int kk = 0; kk < 2; ++kk) {
            bf16x8 af[4], bq[8];
#pragma unroll
            for (int i = 0; i < 4; ++i)
                af[i] = *(const bf16x8*)&As[wr * 64 + i * 16 + l15][kk * 32 + l4 * 8];
#pragma unroll
            for (int j = 0; j < 8; ++j)
                bq[j] = *(const bf16x8*)&Bs[wc * 128 + j * 16 + l15][kk * 32 + l4 * 8];
#pragma unroll
            for (int i = 0; i < 4; ++i)
#pragma unroll
                for (int j = 0; j < 8; ++j)
                    acc[i][j] = __builtin_amdgcn_mfma_f32_16x16x32_bf16(
                        af[i], bq[j], acc[i][j], 0, 0, 0);
        }
        __syncthreads();
    }
    int dB = nBase + wc * 128;
    float vv[8], cp[8], dp0[8], dp1[8];
    int b0 = word ? rowBase / 400 : 0;
    int b1 = word ? (rowBase + 127) / 400 : 0;
#pragma unroll
    for (int j = 0; j < 8; ++j) {
        int d = dB + j * 16 + l15;
        vv[j] = vvec[d];
        cp[j] = word ? covp[d] : 0.f;
        if (word) { dp0[j] = dproj[b0 * H + d]; dp1[j] = dproj[b1 * H + d]; }
    }
#pragma unroll
    for (int i = 0; i < 4; ++i) {
#pragma unroll
        for (int r = 0; r < 4; ++r) {
            int row = rowBase + wr * 64 + i * 16 + l4 * 4 + r;
            int b = word ? (row / 400) : (row / 30);
            float cv = word ? cov[row] : 0.f;
            bool use0 = (b == b0);
            float s = 0.f;
#pragma unroll
            for (int j = 0; j < 8; ++j) {
                float dpv = word ? (use0 ? dp0[j] : dp1[j])
                                 : dproj[b * H + dB + j * 16 + l15];
                float f = acc[i][j][r] + dpv + cv * cp[j];
                s += vv[j] * fast_tanh(f);
            }
            s += __shfl_xor(s, 8, 16);
            s += __shfl_xor(s, 4, 16);
            s += __shfl_xor(s, 2, 16);
            s += __shfl_xor(s, 1, 16);
            if (l15 == 0) atomicAdd(&outp[row], s);
        }
    }
}

__global__ void k_gates(const float* __restrict__ gi, const float* __restrict__ gh,
                        const float* __restrict__ h, float* __restrict__ hnext) {
    int i = blockIdx.x * 256 + threadIdx.x;
    int b = i >> 9, k = i & 511;
    float ir = gi[b * H3 + k], iz = gi[b * H3 + H + k], inn = gi[b * H3 + 2 * H + k];
    float hr = gh[b * H3 + k], hz = gh[b * H3 + H + k], hn = gh[b * H3 + 2 * H + k];
    float r = 1.f / (1.f + __expf(-(ir + hr)));
    float z = 1.f / (1.f + __expf(-(iz + hz)));
    float n = fast_tanh(inn + r * hn);
    hnext[i] = (1.f - z) * n + z * h[i];
}

// fused: blocks [0,B) word masked-softmax+coverage; [B,2B) sent softmax+ctx
__global__ __launch_bounds__(256) void k_smax_sent(
        const float* __restrict__ wscore, const float* __restrict__ wmask,
        const float* __restrict__ cov, float* __restrict__ wattn, float* __restrict__ wcov,
        const float* __restrict__ sscore, const float* __restrict__ smask,
        const float* __restrict__ smb, float* __restrict__ sctx) {
    __shared__ float sc[L];
    __shared__ float red[4];
    int t = threadIdx.x;
    if (blockIdx.x < B) {
        int b = blockIdx.x;
        float mx = -1e30f;
        for (int l = t; l < L; l += 256) { float s = wscore[b * L + l]; sc[l] = s; mx = fmaxf(mx, s); }
        for (int off = 32; off; off >>= 1) mx = fmaxf(mx, __shfl_xor(mx, off));
        if ((t & 63) == 0) red[t >> 6] = mx;
        __syncthreads();
        mx = fmaxf(fmaxf(red[0], red[1]), fmaxf(red[2], red[3]));
        __syncthreads();
        float sm = 0.f;
        for (int l = t; l < L; l += 256) { float e = __expf(sc[l] - mx); sc[l] = e; sm += e; }
        for (int off = 32; off; off >>= 1) sm += __shfl_xor(sm, off);
        if ((t & 63) == 0) red[t >> 6] = sm;
        __syncthreads();
        float Z = red[0] + red[1] + red[2] + red[3];
        __syncthreads();
        float sm2 = 0.f;
        for (int l = t; l < L; l += 256) {
            float a = (sc[l] / Z) * wmask[b * L + l];
            sc[l] = a; sm2 += a;
        }
        for (int off = 32; off; off >>= 1) sm2 += __shfl_xor(sm2, off);
        if ((t & 63) == 0) red[t >> 6] = sm2;
        __syncthreads();
        float Zm = red[0] + red[1] + red[2] + red[3] + 1e-10f;
        for (int l = t; l < L; l += 256) {
            float a = sc[l] / Zm;
            wattn[b * L + l] = a;
            wcov[b * L + l] = cov[b * L + l] + a;
        }
    } else {
        int b = blockIdx.x - B;
        float* sa = sc; float* sa2 = sc + 32; float* smk = sc + 64;
        if (t < S) { sa[t] = sscore[b * S + t]; smk[t] = smask[b * S + t]; }
        __syncthreads();
        if (t < S) {
            float mx = -1e30f;
            for (int l = 0; l < S; ++l) mx = fmaxf(mx, sa[l]);
            float Z = 0.f, Zm = 0.f;
            for (int l = 0; l < S; ++l) { float e = __expf(sa[l] - mx); Z += e; Zm += e * smk[l]; }
            float e = __expf(sa[t] - mx);
            float a = (e / Z) * smk[t];
            sa2[t] = a / (Zm / Z + 1e-10f);
        }
        __syncthreads();
        float a0 = 0.f, a1 = 0.f;
        for (int l = 0; l < S; ++l) {
            const float* r = smb + ((size_t)b * S + l) * M;
            float a = sa2[l];
            a0 += a * r[t]; a1 += a * r[t + 256];
        }
        sctx[b * M + t] = a0; sctx[b * M + t + 256] = a1;
    }
}

// ctx partials: grid (4, B)
__global__ __launch_bounds__(256) void k_ctx_part(
        const float* __restrict__ attn, const float* __restrict__ memb,
        float* __restrict__ ctxp) {
    __shared__ float sa[100];
    int b = blockIdx.y, ch = blockIdx.x, t = threadIdx.x;
    int l0 = ch * 100;
    if (t < 100) sa[t] = attn[b * L + l0 + t];
    __syncthreads();
    float ax = 0.f, ay = 0.f;
    const float* base = memb + ((size_t)b * L + l0) * M + t * 2;
#pragma unroll 4
    for (int l = 0; l < 100; ++l) {
        float2 m2 = *(const float2*)(base + (size_t)l * M);
        float a = sa[l];
        ax += a * m2.x; ay += a * m2.y;
    }
    float* o = ctxp + ((size_t)(ch * B + b)) * M + t * 2;
    o[0] = ax; o[1] = ay;
}

// reduce ctx partials -> wctx (output) AND cat[:, 0:512]
__global__ void k_ctx_red(const float* __restrict__ ctxp, float* __restrict__ wctx,
                          float* __restrict__ cat) {
    int j = blockIdx.x * 256 + threadIdx.x;  // B*M
    float v = ctxp[j] + ctxp[B * M + j] + ctxp[2 * B * M + j] + ctxp[3 * B * M + j];
    wctx[j] = v;
    int b = j >> 9, c = j & 511;
    cat[b * H3 + c] = v;
}

// blocks [0,512): cat[:, 512:1536]; blocks [512, 512+B): p_gen
__global__ void k_catpgen(const float* __restrict__ sctx, const float* __restrict__ hlast,
                          const float* __restrict__ wctx, const float* __restrict__ yemb,
                          const float* __restrict__ pw, const float* __restrict__ pb,
                          float* __restrict__ cat, float* __restrict__ pg) {
    int bb = blockIdx.x, t = threadIdx.x;
    if (bb < 512) {
        int i = bb * 256 + t;        // B * 1024
        int b = i >> 10, c = i & 1023;
        cat[b * H3 + 512 + c] = (c < 512) ? sctx[b * 512 + c] : hlast[b * 512 + c - 512];
    } else {
        int b = bb - 512;
        if (t < 64) {
            float s = 0.f;
            for (int i = t; i < EMB + H + 2 * M; i += 64) {
                float x = (i < 512) ? wctx[b * H + i]
                        : (i < 1024) ? sctx[b * H + i - 512]
                        : (i < 1536) ? hlast[b * H + i - 1024]
                                     : yemb[b * EMB + i - 1536];
                s += x * pw[i];
            }
            for (int off = 32; off; off >>= 1) s += __shfl_xor(s, off);
            if (t == 0) pg[b] = 1.f / (1.f + __expf(-(s + pb[0])));
        }
    }
}

// vocab softmax partials: grid (10, B); chunk = 5000 cols
__global__ __launch_bounds__(256) void k_vpart(
        const float* __restrict__ logits, float* __restrict__ pm, float* __restrict__ ps) {
    __shared__ float wm[4], wsv[4];
    int b = blockIdx.y, c = blockIdx.x, t = threadIdx.x;
    const float4* row = (const float4*)(logits + (size_t)b * V) + c * 1250;
    float m = -3e38f, s = 0.f;
    for (int i = t; i < 1250; i += 256) {
        float4 x = row[i];
        float m4 = fmaxf(fmaxf(x.x, x.y), fmaxf(x.z, x.w));
        if (m4 > m) { s *= __expf(m - m4); m = m4; }
        s += __expf(x.x - m) + __expf(x.y - m) + __expf(x.z - m) + __expf(x.w - m);
    }
    for (int off = 32; off; off >>= 1) {
        float mo = __shfl_xor(m, off), so = __shfl_xor(s, off);
        float mn = fmaxf(m, mo);
        s = s * __expf(m - mn) + so * __expf(mo - mn);
        m = mn;
    }
    if ((t & 63) == 0) { wm[t >> 6] = m; wsv[t >> 6] = s; }
    __syncthreads();
    if (t == 0) {
        float M2 = fmaxf(fmaxf(wm[0], wm[1]), fmaxf(wm[2], wm[3]));
        float S2 = wsv[0] * __expf(wm[0] - M2) + wsv[1] * __expf(wm[1] - M2) +
                   wsv[2] * __expf(wm[2] - M2) + wsv[3] * __expf(wm[3] - M2);
        pm[b * 10 + c] = M2; ps[b * 10 + c] = S2;
    }
}

// final dist write: grid (25, B); 2048 cols per block
__global__ __launch_bounds__(256) void k_vwrite(
        const float* __restrict__ logits, const float* __restrict__ pm,
        const float* __restrict__ ps, const float* __restrict__ pgen,
        float* __restrict__ fd) {
    int b = blockIdx.y, t = threadIdx.x;
    float M2 = -3e38f;
#pragma unroll
    for (int c = 0; c < 10; ++c) M2 = fmaxf(M2, pm[b * 10 + c]);
    float S2 = 0.f;
#pragma unroll
    for (int c = 0; c < 10; ++c) S2 += ps[b * 10 + c] * __expf(pm[b * 10 + c] - M2);
    float inv = pgen[b] / S2;
    int col0 = blockIdx.x * 2048 + t * 8;
    float* outb = fd + (size_t)b * VO;
    if (col0 + 8 <= V) {
        const float4* lp = (const float4*)(logits + (size_t)b * V + col0);
        float4 x = lp[0], z = lp[1];
        *(float2*)(outb + col0)     = make_float2(inv * __expf(x.x - M2), inv * __expf(x.y - M2));
        *(float2*)(outb + col0 + 2) = make_float2(inv * __expf(x.z - M2), inv * __expf(x.w - M2));
        *(float2*)(outb + col0 + 4) = make_float2(inv * __expf(z.x - M2), inv * __expf(z.y - M2));
        *(float2*)(outb + col0 + 6) = make_float2(inv * __expf(z.z - M2), inv * __expf(z.w - M2));
    } else {
#pragma unroll
        for (int k = 0; k < 8; k += 2) {
            int c = col0 + k;
            if (c + 2 <= VO) {
                float2 o;
                o.x = (c < V)     ? inv * __expf(logits[(size_t)b * V + c] - M2) : 0.f;
                o.y = (c + 1 < V) ? inv * __expf(logits[(size_t)b * V + c + 1] - M2) : 0.f;
                *(float2*)(outb + c) = o;
            }
        }
    }
}

__global__ void k_scatter(const int* __restrict__ oov, const float* __restrict__ wattn,
                          const float* __restrict__ pgen, float* __restrict__ fd) {
    int i = blockIdx.x * 256 + threadIdx.x;
    int b = i / L;
    float w = (1.f - pgen[b]) * wattn[i];
    atomicAdd(&fd[(size_t)b * VO + oov[i]], w);
}

extern "C" void kernel_launch(void* const* d_in, const int* in_sizes, int n_in,
                              void* d_out, int out_size, void* d_ws, size_t ws_size,
                              hipStream_t stream) {
    const float* h     = (const float*)d_in[0];
    const float* wmb   = (const float*)d_in[1];
    const float* smb   = (const float*)d_in[2];
    const float* wmask = (const float*)d_in[3];
    const float* smask = (const float*)d_in[4];
    const float* cov   = (const float*)d_in[5];
    const float* emb   = (const float*)d_in[6];
    const float* Wih   = (const float*)d_in[7];
    const float* Whh   = (const float*)d_in[8];
    const float* bih   = (const float*)d_in[9];
    const float* bhh   = (const float*)d_in[10];
    const float* Wmpw  = (const float*)d_in[11];
    const float* Wdpw  = (const float*)d_in[12];
    const float* bdpw  = (const float*)d_in[13];
    const float* vw    = (const float*)d_in[14];
    const float* covp  = (const float*)d_in[15];
    const float* Wmps  = (const float*)d_in[16];
    const float* Wdps  = (const float*)d_in[17];
    const float* bdps  = (const float*)d_in[18];
    const float* vs    = (const float*)d_in[19];
    const float* pw    = (const float*)d_in[20];
    const float* pb    = (const float*)d_in[21];
    const float* vd1w  = (const float*)d_in[22];
    const float* vd1b  = (const float*)d_in[23];
    const float* vd2w  = (const float*)d_in[24];
    const float* vd2b  = (const float*)d_in[25];
    const int*   y     = (const int*)d_in[26];
    const int*   oov   = (const int*)d_in[27];

    float* out   = (float*)d_out;
    float* fd    = out;
    float* hnext = out + O_HN;
    float* wctx  = out + O_WCTX;
    float* wattn = out + O_WATTN;
    float* pgen  = out + O_PGEN;
    float* wcov  = out + O_WCOV;

    float* ws     = (float*)d_ws;
    float* yemb   = ws;
    float* gi     = yemb + B * EMB;
    float* gh     = gi + B * H3;
    float* dpw    = gh + B * H3;
    float* dps    = dpw + B * H;
    float* wscore = dps + B * H;
    float* sscore = wscore + B * L;
    float* sctx   = sscore + B * S;
    float* hid    = sctx + B * M;
    float* logits = hid + B * H;
    float* cat    = gi;      // gi consumed by k_gates before cat is written
    float* ctxp   = logits;  // ctxp consumed by k_ctx_red before logits written
    short* wb     = (short*)(logits + (size_t)B * V);
    short* wb_ih  = wb;
    short* wb_hh  = wb_ih + H3 * EMB;
    short* wb_dpw = wb_hh + H3 * H;
    short* wb_dps = wb_dpw + H * H;
    short* wb_mpw = wb_dps + H * H;
    short* wb_mps = wb_mpw + H * M;
    short* wb_v1  = wb_mps + H * M;
    float* pm     = (float*)(wb_v1 + H * H3);
    float* psum   = pm + B * 10;

    k_init<<<2583, 256, 0, stream>>>(bih, bhh, bdpw, bdps, vd1b, emb, y,
                                     gi, gh, dpw, dps, hid, wscore, sscore, yemb);
    k_cvtw<<<1376, 256, 0, stream>>>(Wih, Whh, Wdpw, Wdps, Wmpw, Wmps, vd1w,
                                     wb_ih, wb_hh, wb_dpw, wb_dps, wb_mpw, wb_mps, wb_v1);
    // gi += yemb@Wih^T (12 tiles, K=128, ksplit 1) ; gh += h@Whh^T (12 tiles, K=512, ksplit 2)
    k_mmsk<<<36, 256, 0, stream>>>(yemb, wb_ih, gi, 128, 12, 1,
                                   h, wb_hh, gh, 512, 12, 2);
    k_gates<<<256, 256, 0, stream>>>(gi, gh, h, hnext);
    // dpw, dps: each 4 tiles, K=512, ksplit 2
    k_mmsk<<<16, 256, 0, stream>>>(hnext, wb_dpw, dpw, 512, 4, 2,
                                   hnext, wb_dps, dps, 512, 4, 2);
    k_feat2<<<dim3(2, 430), 256, 0, stream>>>(wmb, wb_mpw, dpw, cov, covp, vw, wscore,
                                              smb, wb_mps, dps, vs, sscore);
    k_smax_sent<<<2 * B, 256, 0, stream>>>(wscore, wmask, cov, wattn, wcov,
                                           sscore, smask, smb, sctx);
    k_ctx_part<<<dim3(4, B), 256, 0, stream>>>(wattn, wmb, ctxp);
    k_ctx_red<<<(B * M) / 256, 256, 0, stream>>>(ctxp, wctx, cat);
    k_catpgen<<<512 + B, 256, 0, stream>>>(sctx, hnext, wctx, yemb, pw, pb, cat, pgen);
    // hid += cat@vd1w^T (4 tiles, K=1536, ksplit 6)
    k_mmsk<<<24, 256, 0, stream>>>(cat, wb_v1, hid, 1536, 4, 6,
                                   nullptr, nullptr, nullptr, 64, 1, 0);
    k_mm128<<<(V + 127) / 128, 256, 0, stream>>>(hid, vd2w, vd2b, logits, H, V, V);
    k_vpart<<<dim3(10, B), 256, 0, stream>>>(logits, pm, psum);
    k_vwrite<<<dim3(25, B), 256, 0, stream>>>(logits, pm, psum, pgen, fd);
    k_scatter<<<200, 256, 0, stream>>>(oov, wattn, pgen, fd);
}